// Round 9
// baseline (213.303 us; speedup 1.0000x reference)
//
#include <hip/hip_runtime.h>
#include <math.h>

#define BN     32
#define CN     256
#define HN     56
#define WN     56
#define HWN    (HN * WN)        // 3136
#define HW4    (HWN / 4)        // 784 quads per spatial plane
#define NQB    HW4              // alias: quads per image plane
#define CHW4   (CN * HW4)       // 200704 quads per batch image
#define NPOS   (BN * HWN)       // 100352 positions
#define NQ     (NPOS / 4)       // 25088 position-quads
#define CCH    8                // channels per chunk (K1)
#define CHUNKS (CN / CCH)       // 32 chunks per image
#define PQ     ((size_t)BN * CHUNKS * NQB)   // 802816 quads per partial map
#define SPAN   64               // quads per K3 block
#define NBLK3  (NQ / SPAN)      // 392

typedef float f32x4 __attribute__((ext_vector_type(4)));

static __device__ __forceinline__ f32x4 max4(f32x4 a, f32x4 b) {
    f32x4 r;
    r.x = fmaxf(a.x, b.x); r.y = fmaxf(a.y, b.y);
    r.z = fmaxf(a.z, b.z); r.w = fmaxf(a.w, b.w);
    return r;
}

// r7 lesson: grid.sync costs ~150-200us/sync here — never fuse via coop sync.
// r7 also proved x stays L3-resident across the op (FETCH=102MB for 206MB of
// logical reads) -> downstream x reads are L3 hits with plain caching loads.
// r5->r8 lesson: 128B/512B/1KB strided chunks all give the same reduce time;
// this round tests FULLY LINEAR wave streams (the 6.29 TB/s copy pattern).

// K1: linear-sweep partial reduce.
// 1024 waves (256 blocks x 256 thr); wave = (b, chunk of 8 channels).
// The wave walks its 8 channel planes of image b as ONE 100KB linear region
// (channel planes are contiguous: cc*NQB + 784 == (cc+1)*NQB). Lane L
// accumulates position-quads {64i + L} in 13 register pairs -> no LDS, no
// shuffles. Partials go to the OUTPUT buffer as scratch (25.7MB << 98MB;
// overwritten by K3 afterwards; avoids unknown ws_size risk).
__global__ __launch_bounds__(256) void sa_reduce_lin(const f32x4* __restrict__ x4,
                                                     f32x4* __restrict__ scratch) {
    int t    = blockIdx.x * 256 + threadIdx.x;
    int wv   = t >> 6;          // 0..1023
    int lane = t & 63;
    int b     = wv >> 5;        // image
    int chunk = wv & 31;        // 8-channel chunk

    const f32x4* xp = x4 + (size_t)b * CHW4 + (size_t)(chunk * CCH) * NQB;

    f32x4 sum[13], mx[13];
#pragma unroll
    for (int i = 0; i < 13; ++i) {
        sum[i] = (f32x4){0.0f, 0.0f, 0.0f, 0.0f};
        mx[i]  = (f32x4){-INFINITY, -INFINITY, -INFINITY, -INFINITY};
    }

    for (int cc = 0; cc < CCH; ++cc) {          // rolled: 8 channel planes
        const f32x4* cp = xp + (size_t)cc * NQB;
#pragma unroll
        for (int i = 0; i < 13; ++i) {          // unrolled: 13 wave-loads, 1KB each
            int q = i * 64 + lane;
            if (q < NQB) {                      // only i==12 diverges (784 = 12*64+16)
                f32x4 v = cp[q];
                sum[i] += v;
                mx[i] = max4(mx[i], v);
            }
        }
    }

    f32x4* sumP = scratch;
    f32x4* maxP = scratch + PQ;
    size_t pb = (size_t)(b * CHUNKS + chunk) * NQB;
#pragma unroll
    for (int i = 0; i < 13; ++i) {
        int q = i * 64 + lane;
        if (q < NQB) {
            sumP[pb + q] = sum[i];              // plain stores: K2 re-reads via L2/L3
            maxP[pb + q] = mx[i];
        }
    }
}

// K2: combine 32 chunk-partials per position-quad -> avg/mx maps.
// 25.7MB strided reads, all L3-resident (just written). ~5-7us.
__global__ __launch_bounds__(256) void sa_combine(const f32x4* __restrict__ scratch,
                                                  f32x4* __restrict__ avg4,
                                                  f32x4* __restrict__ mx4) {
    int qq = blockIdx.x * 256 + threadIdx.x;    // 98*256 == NQ exactly
    int b = qq / NQB;
    int s = qq - b * NQB;
    const f32x4* sumP = scratch + (size_t)(b * CHUNKS) * NQB + s;
    const f32x4* maxP = sumP + PQ;

    f32x4 sum = {0.0f, 0.0f, 0.0f, 0.0f};
    f32x4 m   = {-INFINITY, -INFINITY, -INFINITY, -INFINITY};
#pragma unroll 8
    for (int k = 0; k < CHUNKS; ++k) {
        sum += sumP[(size_t)k * NQB];
        m = max4(m, maxP[(size_t)k * NQB]);
    }
    avg4[qq] = sum * (1.0f / (float)CN);
    mx4[qq]  = m;
}

// K3: conv+sigmoid+multiply fused, r8-mul geometry (the good one: 1KB
// contiguous per wave load/store). 392 blocks x 512 threads; block owns a
// 64-quad (256-position) span. Threads t<256 first compute att for the span
// (avg/mx halo reads are L2/L3 hits, coalesced per (kh,kw) step), then all
// 8 waves stream x (plain loads -> L3 hits) and nt-store out.
__global__ __launch_bounds__(512) void sa_convmul(const f32x4* __restrict__ x4,
                                                  const float* __restrict__ avg,
                                                  const float* __restrict__ mxp,
                                                  const float* __restrict__ cw,
                                                  f32x4* __restrict__ out4) {
    __shared__ __align__(16) float s_att[SPAN * 4];   // 256 positions

    int t = threadIdx.x;

    if (t < SPAN * 4) {
        int p  = blockIdx.x * (SPAN * 4) + t;         // 392*256 == NPOS exactly
        int bb = p / HWN;
        int s  = p - bb * HWN;
        int h  = s / WN;
        int w0 = s - h * WN;
        const float* a0 = avg + bb * HWN;
        const float* m0 = mxp + bb * HWN;
        float acc = 0.0f;
#pragma unroll
        for (int kh = 0; kh < 7; ++kh) {
            int hh = h + kh - 3;
            if (hh < 0 || hh >= HN) continue;
#pragma unroll
            for (int kw = 0; kw < 7; ++kw) {
                int ww = w0 + kw - 3;
                if (ww < 0 || ww >= WN) continue;
                int idx = hh * WN + ww;
                acc = fmaf(cw[kh * 7 + kw],      a0[idx], acc);
                acc = fmaf(cw[49 + kh * 7 + kw], m0[idx], acc);
            }
        }
        s_att[t] = 1.0f / (1.0f + expf(-acc));
    }
    __syncthreads();

    int j = t & 63;               // quad within span
    int w = t >> 6;               // wave -> 32-channel chunk

    int q  = blockIdx.x * SPAN + j;
    int b  = q / HW4;             // per-lane: spans may straddle images
    int s4 = q - b * HW4;
    size_t base = (size_t)b * CHW4 + (size_t)(w * 32) * HW4 + s4;

    f32x4 a = *(const f32x4*)&s_att[j * 4];
#pragma unroll 8
    for (int k = 0; k < 32; ++k) {
        size_t gi = base + (size_t)k * HW4;
        f32x4 v = x4[gi];
        v.x *= a.x; v.y *= a.y; v.z *= a.z; v.w *= a.w;
        __builtin_nontemporal_store(v, out4 + gi);
    }
}

extern "C" void kernel_launch(void* const* d_in, const int* in_sizes, int n_in,
                              void* d_out, int out_size, void* d_ws, size_t ws_size,
                              hipStream_t stream) {
    const float* x  = (const float*)d_in[0];
    const float* cw = (const float*)d_in[1];
    float* out = (float*)d_out;

    float* avg = (float*)d_ws;          // NPOS floats (ws known-safe at 1.2MB)
    float* mx  = avg + NPOS;

    // K1: partials into out-buffer scratch (consumed by K2 before K3 overwrites)
    sa_reduce_lin<<<256, 256, 0, stream>>>((const f32x4*)x, (f32x4*)out);

    // K2: partials -> avg/mx
    sa_combine<<<NQ / 256, 256, 0, stream>>>((const f32x4*)out,
                                             (f32x4*)avg, (f32x4*)mx);

    // K3: conv + sigmoid + multiply
    sa_convmul<<<NBLK3, 512, 0, stream>>>((const f32x4*)x, avg, mx, cw,
                                          (f32x4*)out);
}

// Round 14
// 201.640 us; speedup vs baseline: 1.0578x; 1.0578x over previous
//
#include <hip/hip_runtime.h>
#include <math.h>

#define BN   32
#define CN   256
#define HN   56
#define WN   56
#define HWN  (HN * WN)          // 3136
#define HW4  (HWN / 4)          // 784 quads per spatial plane
#define CHW4 (CN * HW4)         // 200704 quads per batch image
#define NPOS (BN * HWN)         // 100352 positions
#define NQ   (NPOS / 4)         // 25088 position-quads
#define SPAN 64                 // quads per block (1KB span)
#define NBLK (NQ / SPAN)        // 392 (exact)

typedef float f32x4 __attribute__((ext_vector_type(4)));

// Session model (r2..r9): time = 122us harness fills (fixed)
//                              + our_traffic / ~6.3 TB/s
//                              + ~33us fixed (dispatch gaps, conv, ramps).
// r7: grid.sync costs 150-200us/sync here — never fuse via coop sync; but it
//     proved x stays L3-resident (FETCH=102MB for 206MB logical reads).
// r9: +51MB scratch traffic cost exactly +8.5us -> kernels are BW-saturated;
//     traffic is at floor (103 HBM read + 103 L3 read + 103 HBM write).
// This round: cut the FIXED term — 3 dispatches -> 2 (conv folded into the
// mul kernel's first phase; standalone conv dispatch and att round-trip gone).

// K1: channel-wise mean & max (r8 version, measured-good in aggregate).
// 392 blocks x 512 threads; block owns a 64-quad (1KB) span of positions;
// wave w reduces channels [w*32, w*32+32). Each load instruction fetches
// 1KB contiguous from one channel plane. 8 partials/quad combined via LDS.
__global__ __launch_bounds__(512) void sa_reduce_kernel(const f32x4* __restrict__ x4,
                                                        f32x4* __restrict__ avg4,
                                                        f32x4* __restrict__ mx4) {
    __shared__ f32x4 s_sum[8][SPAN];
    __shared__ f32x4 s_max[8][SPAN];

    int t = threadIdx.x;
    int j = t & 63;               // quad within block span (lane)
    int w = t >> 6;               // wave 0..7 -> 32-channel chunk

    int q  = blockIdx.x * SPAN + j;
    int b  = q / HW4;             // per-lane: spans may straddle images
    int s4 = q - b * HW4;
    const f32x4* xp = x4 + (size_t)b * CHW4 + (size_t)(w * 32) * HW4 + s4;

    f32x4 sum = {0.0f, 0.0f, 0.0f, 0.0f};
    f32x4 m   = {-INFINITY, -INFINITY, -INFINITY, -INFINITY};
#pragma unroll 8
    for (int k = 0; k < 32; ++k) {
        f32x4 v = xp[(size_t)k * HW4];
        sum += v;
        m.x = fmaxf(m.x, v.x);
        m.y = fmaxf(m.y, v.y);
        m.z = fmaxf(m.z, v.z);
        m.w = fmaxf(m.w, v.w);
    }
    s_sum[w][j] = sum;
    s_max[w][j] = m;
    __syncthreads();

    if (t < SPAN) {
        f32x4 sa = s_sum[0][t];
        f32x4 ma = s_max[0][t];
#pragma unroll
        for (int p = 1; p < 8; ++p) {
            sa += s_sum[p][t];
            f32x4 mp = s_max[p][t];
            ma.x = fmaxf(ma.x, mp.x);
            ma.y = fmaxf(ma.y, mp.y);
            ma.z = fmaxf(ma.z, mp.z);
            ma.w = fmaxf(ma.w, mp.w);
        }
        int qq = blockIdx.x * SPAN + t;
        avg4[qq] = sa * (1.0f / (float)CN);
        mx4[qq]  = ma;
    }
}

// K2: conv+sigmoid+multiply fused (r9-K3 version, measured-good).
// 392 blocks x 512 threads; block owns a 64-quad (256-position) span.
// Phase a: threads t<256 compute att for the span (avg/mx reads are L2/L3
// hits; conv cost hides under other blocks' streaming). Phase b: all 8
// waves stream x (plain loads -> L3 hits per r7) with 1KB contiguous per
// wave instruction, multiply, nt-store out (never re-read; don't evict x).
__global__ __launch_bounds__(512) void sa_convmul(const f32x4* __restrict__ x4,
                                                  const float* __restrict__ avg,
                                                  const float* __restrict__ mxp,
                                                  const float* __restrict__ cw,
                                                  f32x4* __restrict__ out4) {
    __shared__ __align__(16) float s_att[SPAN * 4];   // 256 positions

    int t = threadIdx.x;

    if (t < SPAN * 4) {
        int p  = blockIdx.x * (SPAN * 4) + t;         // 392*256 == NPOS exactly
        int bb = p / HWN;
        int s  = p - bb * HWN;
        int h  = s / WN;
        int w0 = s - h * WN;
        const float* a0 = avg + bb * HWN;
        const float* m0 = mxp + bb * HWN;
        float acc = 0.0f;
#pragma unroll
        for (int kh = 0; kh < 7; ++kh) {
            int hh = h + kh - 3;
            if (hh < 0 || hh >= HN) continue;
#pragma unroll
            for (int kw = 0; kw < 7; ++kw) {
                int ww = w0 + kw - 3;
                if (ww < 0 || ww >= WN) continue;
                int idx = hh * WN + ww;
                acc = fmaf(cw[kh * 7 + kw],      a0[idx], acc);
                acc = fmaf(cw[49 + kh * 7 + kw], m0[idx], acc);
            }
        }
        s_att[t] = 1.0f / (1.0f + expf(-acc));
    }
    __syncthreads();

    int j = t & 63;               // quad within span
    int w = t >> 6;               // wave -> 32-channel chunk

    int q  = blockIdx.x * SPAN + j;
    int b  = q / HW4;
    int s4 = q - b * HW4;
    size_t base = (size_t)b * CHW4 + (size_t)(w * 32) * HW4 + s4;

    f32x4 a = *(const f32x4*)&s_att[j * 4];
#pragma unroll 8
    for (int k = 0; k < 32; ++k) {
        size_t gi = base + (size_t)k * HW4;
        f32x4 v = x4[gi];
        v.x *= a.x; v.y *= a.y; v.z *= a.z; v.w *= a.w;
        __builtin_nontemporal_store(v, out4 + gi);
    }
}

extern "C" void kernel_launch(void* const* d_in, const int* in_sizes, int n_in,
                              void* d_out, int out_size, void* d_ws, size_t ws_size,
                              hipStream_t stream) {
    const float* x  = (const float*)d_in[0];
    const float* cw = (const float*)d_in[1];
    float* out = (float*)d_out;

    float* avg = (float*)d_ws;          // NPOS floats
    float* mx  = avg + NPOS;            // NPOS floats

    sa_reduce_kernel<<<NBLK, 512, 0, stream>>>(
        (const f32x4*)x, (f32x4*)avg, (f32x4*)mx);

    sa_convmul<<<NBLK, 512, 0, stream>>>(
        (const f32x4*)x, avg, mx, cw, (f32x4*)out);
}